// Round 1
// baseline (942.786 us; speedup 1.0000x reference)
//
#include <hip/hip_runtime.h>
#include <hip/hip_bf16.h>

#define H_ 12
#define T_ 64
#define C_ 384
#define TC_ 1152

typedef __attribute__((ext_vector_type(8))) short bf16x8;
typedef __attribute__((ext_vector_type(4))) short bf16x4;
typedef __attribute__((ext_vector_type(2))) short bf16x2;
typedef __attribute__((ext_vector_type(4))) float f32x4;
typedef __attribute__((ext_vector_type(4))) float float4v;

__device__ __forceinline__ short f2b(float f) {
    unsigned u = __builtin_bit_cast(unsigned, f);
    unsigned r = (u + 0x7fffu + ((u >> 16) & 1u)) >> 16;
    return (short)r;
}

// ---------------- K0: prep — convert weights to bf16, build bias table -------
// bias_t layout: [h][j][i]  (j = key idx, i = query idx) for coalesced reads.
__global__ void prep_kernel(const float* __restrict__ qkv_w,
                            const float* __restrict__ proj_w,
                            const float* __restrict__ rel_pos_bias,
                            const int* __restrict__ rel_pos_index,
                            short* __restrict__ wqkv, short* __restrict__ wproj,
                            float* __restrict__ bias_t) {
    const int n1 = TC_ * C_;          // 442368
    const int n2 = C_ * C_;           // 147456
    const int n3 = H_ * T_ * T_;      // 49152
    const int total = n1 + n2 + n3;
    for (int u = blockIdx.x * blockDim.x + threadIdx.x; u < total;
         u += gridDim.x * blockDim.x) {
        if (u < n1) {
            wqkv[u] = f2b(qkv_w[u]);
        } else if (u < n1 + n2) {
            wproj[u - n1] = f2b(proj_w[u - n1]);
        } else {
            int v = u - n1 - n2;          // h*4096 + j*64 + i
            int h = v >> 12;
            int j = (v >> 6) & 63;
            int i = v & 63;
            bias_t[v] = rel_pos_bias[rel_pos_index[i * 64 + j] * H_ + h];
        }
    }
}

// ---------------- K1: QKV GEMM (x fp32 -> bf16 MFMA), scatter to attn layout -
// qkv_ws layout per (b,h): 3 planes of 2048 bf16:
//   which 0 (q, pre-scaled), 1 (k): [t][d]   (t stride 32)
//   which 2 (v):                   [d][t]   (d stride 64)  -> PV B-frags contiguous
__global__ void qkv_gemm(const float* __restrict__ x, const short* __restrict__ wq,
                         const float* __restrict__ qkv_b, short* __restrict__ qkv_ws) {
    __shared__ short As[128][72];
    __shared__ short Bs[128][72];
    const int tid = threadIdx.x;
    const int l = tid & 63;
    const int w = tid >> 6;
    const int wr = w >> 1, wc = w & 1;
    const int lr = l & 15, lg = l >> 4;
    const int tile_n = blockIdx.x % 9;
    const int tile_m = blockIdx.x / 9;

    f32x4 acc[4][4] = {};

    for (int kk = 0; kk < 6; ++kk) {
        // stage A (fp32 -> bf16): 16 threads/row, 8 passes of 16 rows
        {
            const int colA = (tid & 15) * 4;
            const float* srcA = x + (size_t)(tile_m * 128 + (tid >> 4)) * C_ + kk * 64 + colA;
#pragma unroll
            for (int p = 0; p < 8; ++p) {
                float4v v = *reinterpret_cast<const float4v*>(srcA + (size_t)p * 16 * C_);
                bf16x4 bv;
                bv[0] = f2b(v[0]); bv[1] = f2b(v[1]); bv[2] = f2b(v[2]); bv[3] = f2b(v[3]);
                *reinterpret_cast<bf16x4*>(&As[(tid >> 4) + p * 16][colA]) = bv;
            }
        }
        // stage B (bf16 copy): 8 threads/row, 4 passes of 32 rows
        {
            const int colB = (tid & 7) * 8;
            const short* srcB = wq + (size_t)(tile_n * 128 + (tid >> 3)) * C_ + kk * 64 + colB;
#pragma unroll
            for (int p = 0; p < 4; ++p) {
                bf16x8 v = *reinterpret_cast<const bf16x8*>(srcB + (size_t)p * 32 * C_);
                *reinterpret_cast<bf16x8*>(&Bs[(tid >> 3) + p * 32][colB]) = v;
            }
        }
        __syncthreads();
#pragma unroll
        for (int kc = 0; kc < 2; ++kc) {
            bf16x8 af[4], bfr[4];
#pragma unroll
            for (int mt = 0; mt < 4; ++mt)
                af[mt] = *reinterpret_cast<const bf16x8*>(&As[wr * 64 + mt * 16 + lr][kc * 32 + lg * 8]);
#pragma unroll
            for (int nt = 0; nt < 4; ++nt)
                bfr[nt] = *reinterpret_cast<const bf16x8*>(&Bs[wc * 64 + nt * 16 + lr][kc * 32 + lg * 8]);
#pragma unroll
            for (int mt = 0; mt < 4; ++mt)
#pragma unroll
                for (int nt = 0; nt < 4; ++nt)
                    acc[mt][nt] = __builtin_amdgcn_mfma_f32_16x16x32_bf16(af[mt], bfr[nt], acc[mt][nt], 0, 0, 0);
        }
        __syncthreads();
    }

    const float scale = 0.17677669529663687f;  // 32^-0.5
#pragma unroll
    for (int mt = 0; mt < 4; ++mt) {
#pragma unroll
        for (int nt = 0; nt < 4; ++nt) {
            const int gn = tile_n * 128 + wc * 64 + nt * 16 + lr;
            const float bias = qkv_b[gn];
            const int which = gn / C_;
            const int hd = gn - which * C_;
            const int h = hd >> 5, d = hd & 31;
#pragma unroll
            for (int r = 0; r < 4; ++r) {
                const int gm = tile_m * 128 + wr * 64 + mt * 16 + lg * 4 + r;
                const int b = gm >> 6, t = gm & 63;
                float v = acc[mt][nt][r] + bias;
                if (which == 0) v *= scale;
                const size_t base = ((size_t)(b * H_ + h) * 3 + which) * 2048;
                const size_t idx = (which == 2) ? (base + d * 64 + t) : (base + t * 32 + d);
                qkv_ws[idx] = f2b(v);
            }
        }
    }
}

// ---------------- K2: attention — 1 wave per (b,h) --------------------------
__global__ void attn_kernel(const short* __restrict__ qkv_ws,
                            const float* __restrict__ bias_t,
                            short* __restrict__ attn_out) {
    __shared__ short P_lds[4][64][72];
    __shared__ float rinv[4][64];
    const int tid = threadIdx.x;
    const int w = tid >> 6, l = tid & 63;
    const int lr = l & 15, lg = l >> 4;
    const int pair = blockIdx.x * 4 + w;   // b*12 + h
    const int b = pair / 12, h = pair - b * 12;
    const size_t base = (size_t)pair * 3 * 2048;
    const short* qp = qkv_ws + base;
    const short* kp = qkv_ws + base + 2048;
    const short* vp = qkv_ws + base + 4096;

    bf16x8 qf[4], kf[4];
#pragma unroll
    for (int it = 0; it < 4; ++it)
        qf[it] = *reinterpret_cast<const bf16x8*>(qp + (it * 16 + lr) * 32 + lg * 8);
#pragma unroll
    for (int jt = 0; jt < 4; ++jt)
        kf[jt] = *reinterpret_cast<const bf16x8*>(kp + (jt * 16 + lr) * 32 + lg * 8);

    // S^T tiles: s[jt][it] holds S[i][j], i = it*16+lr (col), j = jt*16+lg*4+r (row)
    f32x4 s[4][4];
#pragma unroll
    for (int jt = 0; jt < 4; ++jt)
#pragma unroll
        for (int it = 0; it < 4; ++it)
            s[jt][it] = __builtin_amdgcn_mfma_f32_16x16x32_bf16(kf[jt], qf[it], (f32x4){0.f, 0.f, 0.f, 0.f}, 0, 0, 0);

    // add rel-pos bias: bias_t[h][j][i]
    const float* bh = bias_t + h * 4096;
#pragma unroll
    for (int jt = 0; jt < 4; ++jt)
#pragma unroll
        for (int it = 0; it < 4; ++it)
#pragma unroll
            for (int r = 0; r < 4; ++r) {
                const int i = it * 16 + lr;
                const int j = jt * 16 + lg * 4 + r;
                s[jt][it][r] += bh[j * 64 + i];
            }

    // softmax over j for each query row i = it*16+lr
#pragma unroll
    for (int it = 0; it < 4; ++it) {
        float m = -1e30f;
#pragma unroll
        for (int jt = 0; jt < 4; ++jt)
#pragma unroll
            for (int r = 0; r < 4; ++r) m = fmaxf(m, s[jt][it][r]);
        m = fmaxf(m, __shfl_xor(m, 16, 64));
        m = fmaxf(m, __shfl_xor(m, 32, 64));
        float sum = 0.f;
#pragma unroll
        for (int jt = 0; jt < 4; ++jt)
#pragma unroll
            for (int r = 0; r < 4; ++r) {
                const float p = __expf(s[jt][it][r] - m);
                s[jt][it][r] = p;
                sum += p;
            }
        sum += __shfl_xor(sum, 16, 64);
        sum += __shfl_xor(sum, 32, 64);
        const int i = it * 16 + lr;
#pragma unroll
        for (int jt = 0; jt < 4; ++jt)
#pragma unroll
            for (int rp = 0; rp < 2; ++rp) {
                bf16x2 pv;
                pv[0] = f2b(s[jt][it][rp * 2]);
                pv[1] = f2b(s[jt][it][rp * 2 + 1]);
                const int j = jt * 16 + lg * 4 + rp * 2;
                *reinterpret_cast<bf16x2*>(&P_lds[w][i][j]) = pv;
            }
        if (lg == 0) rinv[w][i] = 1.0f / sum;
    }

    // V B-frags (v stored [d][t])
    bf16x8 vf[2][2];
#pragma unroll
    for (int dt = 0; dt < 2; ++dt)
#pragma unroll
        for (int jc = 0; jc < 2; ++jc)
            vf[dt][jc] = *reinterpret_cast<const bf16x8*>(vp + (dt * 16 + lr) * 64 + jc * 32 + lg * 8);

    // O = P @ V
    f32x4 o[4][2] = {};
#pragma unroll
    for (int it = 0; it < 4; ++it)
#pragma unroll
        for (int jc = 0; jc < 2; ++jc) {
            bf16x8 pf = *reinterpret_cast<const bf16x8*>(&P_lds[w][it * 16 + lr][jc * 32 + lg * 8]);
#pragma unroll
            for (int dt = 0; dt < 2; ++dt)
                o[it][dt] = __builtin_amdgcn_mfma_f32_16x16x32_bf16(pf, vf[dt][jc], o[it][dt], 0, 0, 0);
        }

    // epilogue: divide by rowsum, write bf16 [b*64+t][h*32+d]
#pragma unroll
    for (int it = 0; it < 4; ++it)
#pragma unroll
        for (int dt = 0; dt < 2; ++dt)
#pragma unroll
            for (int r = 0; r < 4; ++r) {
                const int t = it * 16 + lg * 4 + r;
                const int d = dt * 16 + lr;
                const float v = o[it][dt][r] * rinv[w][t];
                attn_out[((size_t)b * 64 + t) * C_ + h * 32 + d] = f2b(v);
            }
}

// ---------------- K3: proj GEMM (bf16 -> fp32 out) --------------------------
__global__ void proj_gemm(const short* __restrict__ a, const short* __restrict__ wp,
                          const float* __restrict__ proj_b, float* __restrict__ out) {
    __shared__ short As[128][72];
    __shared__ short Bs[128][72];
    const int tid = threadIdx.x;
    const int l = tid & 63;
    const int w = tid >> 6;
    const int wr = w >> 1, wc = w & 1;
    const int lr = l & 15, lg = l >> 4;
    const int tile_n = blockIdx.x % 3;
    const int tile_m = blockIdx.x / 3;

    f32x4 acc[4][4] = {};

    for (int kk = 0; kk < 6; ++kk) {
        {
            const int col = (tid & 7) * 8;
            const short* srcA = a + (size_t)(tile_m * 128 + (tid >> 3)) * C_ + kk * 64 + col;
            const short* srcB = wp + (size_t)(tile_n * 128 + (tid >> 3)) * C_ + kk * 64 + col;
#pragma unroll
            for (int p = 0; p < 4; ++p) {
                bf16x8 va = *reinterpret_cast<const bf16x8*>(srcA + (size_t)p * 32 * C_);
                *reinterpret_cast<bf16x8*>(&As[(tid >> 3) + p * 32][col]) = va;
                bf16x8 vb = *reinterpret_cast<const bf16x8*>(srcB + (size_t)p * 32 * C_);
                *reinterpret_cast<bf16x8*>(&Bs[(tid >> 3) + p * 32][col]) = vb;
            }
        }
        __syncthreads();
#pragma unroll
        for (int kc = 0; kc < 2; ++kc) {
            bf16x8 af[4], bfr[4];
#pragma unroll
            for (int mt = 0; mt < 4; ++mt)
                af[mt] = *reinterpret_cast<const bf16x8*>(&As[wr * 64 + mt * 16 + lr][kc * 32 + lg * 8]);
#pragma unroll
            for (int nt = 0; nt < 4; ++nt)
                bfr[nt] = *reinterpret_cast<const bf16x8*>(&Bs[wc * 64 + nt * 16 + lr][kc * 32 + lg * 8]);
#pragma unroll
            for (int mt = 0; mt < 4; ++mt)
#pragma unroll
                for (int nt = 0; nt < 4; ++nt)
                    acc[mt][nt] = __builtin_amdgcn_mfma_f32_16x16x32_bf16(af[mt], bfr[nt], acc[mt][nt], 0, 0, 0);
        }
        __syncthreads();
    }

#pragma unroll
    for (int mt = 0; mt < 4; ++mt) {
#pragma unroll
        for (int nt = 0; nt < 4; ++nt) {
            const int gn = tile_n * 128 + wc * 64 + nt * 16 + lr;
            const float bias = proj_b[gn];
#pragma unroll
            for (int r = 0; r < 4; ++r) {
                const int gm = tile_m * 128 + wr * 64 + mt * 16 + lg * 4 + r;
                out[(size_t)gm * C_ + gn] = acc[mt][nt][r] + bias;
            }
        }
    }
}

// ---------------- launch ----------------------------------------------------
extern "C" void kernel_launch(void* const* d_in, const int* in_sizes, int n_in,
                              void* d_out, int out_size, void* d_ws, size_t ws_size,
                              hipStream_t stream) {
    const float* x = (const float*)d_in[0];
    const float* qkv_w = (const float*)d_in[1];
    const float* qkv_b = (const float*)d_in[2];
    const float* proj_w = (const float*)d_in[3];
    const float* proj_b = (const float*)d_in[4];
    const float* rel_pos_bias = (const float*)d_in[5];
    const int* rel_pos_index = (const int*)d_in[6];
    float* out = (float*)d_out;

    char* ws = (char*)d_ws;
    short* wqkv   = (short*)(ws);                        // 884,736 B
    short* wproj  = (short*)(ws + 884736);               // 294,912 B
    float* bias_t = (float*)(ws + 1179648);              // 196,608 B
    short* qkv_ws = (short*)(ws + 1376256);              // 301,989,888 B
    short* attn_o = (short*)(ws + 303366144);            // 100,663,296 B  (total ~404 MB)

    hipLaunchKernelGGL(prep_kernel, dim3(624), dim3(256), 0, stream,
                       qkv_w, proj_w, rel_pos_bias, rel_pos_index, wqkv, wproj, bias_t);
    hipLaunchKernelGGL(qkv_gemm, dim3(9216), dim3(256), 0, stream, x, wqkv, qkv_b, qkv_ws);
    hipLaunchKernelGGL(attn_kernel, dim3(6144), dim3(256), 0, stream, qkv_ws, bias_t, attn_o);
    hipLaunchKernelGGL(proj_gemm, dim3(3072), dim3(256), 0, stream, attn_o, wproj, proj_b, out);
}